// Round 9
// baseline (18.603 us; speedup 1.0000x reference)
//
#include <hip/hip_runtime.h>

#define B 16
#define T 2048
#define D 1024
#define NSLICE 32            // slice-blocks per batch slot
#define SLICE (D / NSLICE)   // 32 floats = 8 float4 per block
#define NRP 64               // row phases (512 threads / 8 float4 cols)

#define FMA4(c, v, a)                    \
    do {                                 \
        (a).x = fmaf((c), (v).x, (a).x); \
        (a).y = fmaf((c), (v).y, (a).y); \
        (a).z = fmaf((c), (v).z, (a).z); \
        (a).w = fmaf((c), (v).w, (a).w); \
    } while (0)

// R8 structure (single kernel, slice-columns, single-writer stores, sorted
// batch pairing, no atomics/fences/scratch) with 2x waves and 2x unroll:
// 512-thread blocks (64 row-phases) x 512 blocks = 16 waves/CU, unroll 8
// -> ~4x in-flight bytes per CU vs R8. R8's sorted-pairing null proved the
// limiter is NOT per-CU work distribution; the surviving theories are
// per-CU in-flight/latency cap (this kernel tests: 4x in-flight) or
// aggregate pattern BW / fixed overhead (if unchanged, probe next round).
__global__ __launch_bounds__(512, 4) void fused3_kernel(
    const float* __restrict__ input,
    const int* __restrict__ lengths,
    const float* __restrict__ weights,
    float* __restrict__ out) {
    const int j   = blockIdx.x >> 5;   // batch slot 0..15
    const int s   = blockIdx.x & 31;   // slice
    const int tid = threadIdx.x;
    const int c   = tid & 7;           // float4 column within slice
    const int rp  = tid >> 3;          // row phase 0..63

    // ---- sorted batch pairing (uniform; compile-time indices only) ----
    unsigned key[B];
#pragma unroll
    for (int i = 0; i < B; ++i)
        key[i] = ((unsigned)lengths[i] << 4) | (unsigned)i;
#pragma unroll
    for (int pass = 0; pass < B; ++pass) {
#pragma unroll
        for (int i = (pass & 1); i + 1 < B; i += 2) {
            const unsigned a = key[i], b2 = key[i + 1];
            if (a < b2) { key[i] = b2; key[i + 1] = a; }   // descending
        }
    }
    const int jj = (j < 8) ? j : 23 - j;   // rank j or rank 15-(j-8)
    unsigned k = 0;
#pragma unroll
    for (int i = 0; i < B; ++i)            // select chain, no runtime index
        if (i == jj) k = key[i];
    const int b   = (int)(k & 15u);
    const int len = (int)(k >> 4);

    // ---- coeff table exp(w) -> LDS; denominator from the same values ----
    __shared__ float cf[T];                // 8 KB
    __shared__ float red[8];
    float lsum = 0.f;
#pragma unroll
    for (int i = 0; i < 4; ++i) {
        const float e = expf(weights[tid * 4 + i]);
        cf[tid * 4 + i] = e;
        lsum += e;
    }
#pragma unroll
    for (int off = 32; off > 0; off >>= 1)
        lsum += __shfl_xor(lsum, off);
    if ((tid & 63) == 0) red[tid >> 6] = lsum;
    __syncthreads();
    const float inv = 1.f / (red[0] + red[1] + red[2] + red[3] +
                             red[4] + red[5] + red[6] + red[7]);

    const float4* __restrict__ in4 =
        (const float4*)input + (size_t)b * T * (D / 4) + s * (SLICE / 4) + c;

    float4 acc = make_float4(0.f, 0.f, 0.f, 0.f);

    // full 64-row groups; unroll 8 keeps 8 float4 loads in flight/thread
    const int nfull = len >> 6;
    const float4* p = in4 + (size_t)rp * (D / 4);
#pragma unroll 8
    for (int it = 0; it < nfull; ++it) {
        const float  cw = cf[it * 64 + rp];
        const float4 v  = p[(size_t)it * 64 * (D / 4)];
        FMA4(cw, v, acc);
    }
    // tail rows
    const int r = (nfull << 6) + rp;
    if (r < len) {
        const float  cw = cf[r];
        const float4 v  = in4[(size_t)r * (D / 4)];
        FMA4(cw, v, acc);
    }

    // ---- LDS tree-reduce over the 64 row-phases ----
    __shared__ float4 lds[NRP][8];         // 8 KB
    lds[rp][c] = acc;
    __syncthreads();
#pragma unroll
    for (int off = 32; off > 0; off >>= 1) {
        if (rp < off) {
            const float4 o = lds[rp + off][c];
            acc.x += o.x; acc.y += o.y; acc.z += o.z; acc.w += o.w;
            lds[rp][c] = acc;
        }
        __syncthreads();
    }

    if (tid < 8) {   // rp==0, c==tid: single writer of out[b, s*32+...]
        const float4 r4 = make_float4(acc.x * inv, acc.y * inv,
                                      acc.z * inv, acc.w * inv);
        ((float4*)out)[b * (D / 4) + s * (SLICE / 4) + tid] = r4;
    }
}

extern "C" void kernel_launch(void* const* d_in, const int* in_sizes, int n_in,
                              void* d_out, int out_size, void* d_ws, size_t ws_size,
                              hipStream_t stream) {
    const float* input   = (const float*)d_in[0];
    const int*   lengths = (const int*)d_in[1];
    const float* weights = (const float*)d_in[2];
    float* out = (float*)d_out;

    fused3_kernel<<<B * NSLICE, 512, 0, stream>>>(input, lengths, weights, out);
}